// Round 3
// baseline (6702.682 us; speedup 1.0000x reference)
//
#include <hip/hip_runtime.h>

#define STEPS 96
#define HDIM 4096
#define IDIM 1024
#define BLOCKS 256
#define THREADS 512
#define WAVES 8
#define ROWS_PER_BLOCK 16  // 2 rows per wave

// ---------- bf16 pack/unpack ----------
__device__ inline unsigned short f2bf(float f) {
  unsigned u = __float_as_uint(f);
  u += 0x7fffu + ((u >> 16) & 1u);
  return (unsigned short)(u >> 16);
}
__device__ inline unsigned pack2(float a, float b) {
  return (unsigned)f2bf(a) | ((unsigned)f2bf(b) << 16);
}
__device__ inline float blo(unsigned p) { return __uint_as_float(p << 16); }
__device__ inline float bhi(unsigned p) { return __uint_as_float(p & 0xffff0000u); }

__device__ inline float wave_reduce(float v) {
#pragma unroll
  for (int off = 32; off > 0; off >>= 1) v += __shfl_xor(v, off);
  return v;
}

struct Params {
  const float *x, *Wih0, *bih0, *Whh0, *bhh0, *Wih1, *bih1, *Whh1, *bhh1, *Wfc, *bfc;
  float *h0, *h1;            // [HDIM] each (single-buffered; phases are barrier-separated)
  unsigned *leaf, *root, *flag;
  float *out;
};

// monotonic hierarchical grid barrier; gen = 1,2,3,...
__device__ inline void grid_barrier(const Params& p, unsigned gen) {
  __syncthreads();
  if (threadIdx.x == 0) {
    __threadfence();
    const int g = blockIdx.x & 7;
    unsigned prev = __hip_atomic_fetch_add(p.leaf + g * 32, 1u, __ATOMIC_RELAXED,
                                           __HIP_MEMORY_SCOPE_AGENT);
    if (prev == gen * (BLOCKS / 8) - 1) {
      unsigned r = __hip_atomic_fetch_add(p.root, 1u, __ATOMIC_RELAXED,
                                          __HIP_MEMORY_SCOPE_AGENT);
      if (r == gen * 8 - 1) {
        __hip_atomic_store(p.flag, gen, __ATOMIC_RELEASE, __HIP_MEMORY_SCOPE_AGENT);
      }
    }
    while (__hip_atomic_load(p.flag, __ATOMIC_RELAXED, __HIP_MEMORY_SCOPE_AGENT) < gen) {
      __builtin_amdgcn_s_sleep(1);
    }
    __threadfence();
  }
  __syncthreads();
}

__global__ void __launch_bounds__(THREADS, 2) rnn_kernel(Params p) {
  // W_hh1 rows of this block, packed bf16 pairs: [r][j*128 + l*2 + s] <-> cols (2u, 2u+1)
  __shared__ unsigned whh1[ROWS_PER_BLOCK * (HDIM / 2)];  // 128 KB
  __shared__ float win[IDIM + STEPS];                     // sliding window
  __shared__ float red[WAVES];

  const int tid = threadIdx.x, lane = tid & 63, wv = tid >> 6, blk = blockIdx.x;
  const int r0 = blk * ROWS_PER_BLOCK + wv * 2;
  const int r1 = r0 + 1;

  // ---- setup: stage W_hh1 rows into LDS (col = 2u exactly) ----
  for (int rr = 0; rr < ROWS_PER_BLOCK; ++rr) {
    const float* src = p.Whh1 + (size_t)(blk * ROWS_PER_BLOCK + rr) * HDIM;
    for (int u = tid; u < HDIM / 2; u += THREADS) {
      float2 f = *reinterpret_cast<const float2*>(src + 2 * u);
      whh1[rr * (HDIM / 2) + u] = pack2(f.x, f.y);
    }
  }
  for (int i = tid; i < IDIM; i += THREADS) win[i] = p.x[i];

  // ---- setup: register-resident packed weights ----
  unsigned wA_ih0[8], wB_ih0[8];
#pragma unroll
  for (int j = 0; j < 8; ++j) {
    const float* s0 = p.Wih0 + (size_t)r0 * IDIM + j * 128 + lane;
    const float* s1 = p.Wih0 + (size_t)r1 * IDIM + j * 128 + lane;
    wA_ih0[j] = pack2(s0[0], s0[64]);
    wB_ih0[j] = pack2(s1[0], s1[64]);
  }
  unsigned wA_hh0[32], wB_hh0[32], wA_ih1[32], wB_ih1[32];
#pragma unroll
  for (int j = 0; j < 16; ++j) {
    float4 f;
    f = *reinterpret_cast<const float4*>(p.Whh0 + (size_t)r0 * HDIM + j * 256 + lane * 4);
    wA_hh0[2 * j] = pack2(f.x, f.y); wA_hh0[2 * j + 1] = pack2(f.z, f.w);
    f = *reinterpret_cast<const float4*>(p.Whh0 + (size_t)r1 * HDIM + j * 256 + lane * 4);
    wB_hh0[2 * j] = pack2(f.x, f.y); wB_hh0[2 * j + 1] = pack2(f.z, f.w);
    f = *reinterpret_cast<const float4*>(p.Wih1 + (size_t)r0 * HDIM + j * 256 + lane * 4);
    wA_ih1[2 * j] = pack2(f.x, f.y); wA_ih1[2 * j + 1] = pack2(f.z, f.w);
    f = *reinterpret_cast<const float4*>(p.Wih1 + (size_t)r1 * HDIM + j * 256 + lane * 4);
    wB_ih1[2 * j] = pack2(f.x, f.y); wB_ih1[2 * j + 1] = pack2(f.z, f.w);
  }
  unsigned wfcp[4];
  {
    float4 f = *reinterpret_cast<const float4*>(p.Wfc + tid * 8);
    wfcp[0] = pack2(f.x, f.y); wfcp[1] = pack2(f.z, f.w);
    f = *reinterpret_cast<const float4*>(p.Wfc + tid * 8 + 4);
    wfcp[2] = pack2(f.x, f.y); wfcp[3] = pack2(f.z, f.w);
  }
  const float bias0a = p.bih0[r0] + p.bhh0[r0];
  const float bias0b = p.bih0[r1] + p.bhh0[r1];
  const float bias1a = p.bih1[r0] + p.bhh1[r0];
  const float bias1b = p.bih1[r1] + p.bhh1[r1];
  const float bfc = p.bfc[0];

  __syncthreads();

  float p1a = 0.f, p1b = 0.f;  // carried per-lane partials of Whh0 . h0 (zeros at t=0)
  unsigned gen = 0;

  for (int t = 0; t < STEPS; ++t) {
    // ---- phase 1: h0 = tanh(Wih0 @ win[t:] + carried Whh0-partial + bias) ----
    float a1 = p1a, b1 = p1b;
#pragma unroll
    for (int j = 0; j < 8; ++j) {
      float v0 = win[t + j * 128 + lane];
      float v1 = win[t + j * 128 + 64 + lane];
      a1 += v0 * blo(wA_ih0[j]) + v1 * bhi(wA_ih0[j]);
      b1 += v0 * blo(wB_ih0[j]) + v1 * bhi(wB_ih0[j]);
    }
    a1 = wave_reduce(a1);
    b1 = wave_reduce(b1);
    if (lane == 0) {
      p.h0[r0] = tanhf(a1 + bias0a);
      p.h0[r1] = tanhf(b1 + bias0b);
    }

    // ---- slot 2 (pre-barrier, latency-slack): Whh1 @ h1_old from LDS weights ----
    float a2 = 0.f, b2 = 0.f;
    {
      const unsigned* wl0 = whh1 + (wv * 2) * (HDIM / 2);
      const unsigned* wl1 = wl0 + (HDIM / 2);
#pragma unroll
      for (int j = 0; j < 16; ++j) {
        float4 v = *reinterpret_cast<const float4*>(p.h1 + j * 256 + lane * 4);
        unsigned c0 = wl0[j * 128 + lane * 2], c1 = wl0[j * 128 + lane * 2 + 1];
        unsigned d0 = wl1[j * 128 + lane * 2], d1 = wl1[j * 128 + lane * 2 + 1];
        a2 += v.x * blo(c0) + v.y * bhi(c0) + v.z * blo(c1) + v.w * bhi(c1);
        b2 += v.x * blo(d0) + v.y * bhi(d0) + v.z * blo(d1) + v.w * bhi(d1);
      }
    }

    grid_barrier(p, ++gen);

    // ---- phase 2: += Wih1 @ h0 ; also compute next step's Whh0 @ h0 partial ----
    float q1a = 0.f, q1b = 0.f;
#pragma unroll
    for (int j = 0; j < 16; ++j) {
      float4 v = *reinterpret_cast<const float4*>(p.h0 + j * 256 + lane * 4);
      a2 += v.x * blo(wA_ih1[2 * j]) + v.y * bhi(wA_ih1[2 * j]) +
            v.z * blo(wA_ih1[2 * j + 1]) + v.w * bhi(wA_ih1[2 * j + 1]);
      b2 += v.x * blo(wB_ih1[2 * j]) + v.y * bhi(wB_ih1[2 * j]) +
            v.z * blo(wB_ih1[2 * j + 1]) + v.w * bhi(wB_ih1[2 * j + 1]);
      q1a += v.x * blo(wA_hh0[2 * j]) + v.y * bhi(wA_hh0[2 * j]) +
             v.z * blo(wA_hh0[2 * j + 1]) + v.w * bhi(wA_hh0[2 * j + 1]);
      q1b += v.x * blo(wB_hh0[2 * j]) + v.y * bhi(wB_hh0[2 * j]) +
             v.z * blo(wB_hh0[2 * j + 1]) + v.w * bhi(wB_hh0[2 * j + 1]);
    }
    a2 = wave_reduce(a2);
    b2 = wave_reduce(b2);
    if (lane == 0) {
      p.h1[r0] = tanhf(a2 + bias1a);
      p.h1[r1] = tanhf(b2 + bias1b);
    }
    p1a = q1a;
    p1b = q1b;

    grid_barrier(p, ++gen);

    // ---- phase 3: y = Wfc @ h1 + b_fc (redundant per block), append to window ----
    {
      float4 v0 = *reinterpret_cast<const float4*>(p.h1 + tid * 8);
      float4 v1 = *reinterpret_cast<const float4*>(p.h1 + tid * 8 + 4);
      float part = v0.x * blo(wfcp[0]) + v0.y * bhi(wfcp[0]) +
                   v0.z * blo(wfcp[1]) + v0.w * bhi(wfcp[1]) +
                   v1.x * blo(wfcp[2]) + v1.y * bhi(wfcp[2]) +
                   v1.z * blo(wfcp[3]) + v1.w * bhi(wfcp[3]);
      part = wave_reduce(part);
      if (lane == 0) red[wv] = part;
    }
    __syncthreads();
    if (tid == 0) {
      float y = bfc;
#pragma unroll
      for (int i = 0; i < WAVES; ++i) y += red[i];
      win[IDIM + t] = y;
      if (blk == 0) p.out[t] = y;
    }
    __syncthreads();
  }
}

extern "C" void kernel_launch(void* const* d_in, const int* in_sizes, int n_in,
                              void* d_out, int out_size, void* d_ws, size_t ws_size,
                              hipStream_t stream) {
  Params p;
  p.x = (const float*)d_in[0];
  p.Wih0 = (const float*)d_in[1];
  p.bih0 = (const float*)d_in[2];
  p.Whh0 = (const float*)d_in[3];
  p.bhh0 = (const float*)d_in[4];
  p.Wih1 = (const float*)d_in[5];
  p.bih1 = (const float*)d_in[6];
  p.Whh1 = (const float*)d_in[7];
  p.bhh1 = (const float*)d_in[8];
  p.Wfc = (const float*)d_in[9];
  p.bfc = (const float*)d_in[10];
  p.out = (float*)d_out;

  // workspace: h0[4096] h1[4096] f32, then barrier counters
  float* hbuf = (float*)d_ws;
  p.h0 = hbuf;
  p.h1 = hbuf + HDIM;
  unsigned* bar = (unsigned*)(hbuf + 2 * HDIM);
  p.leaf = bar;
  p.root = bar + 8 * 32;
  p.flag = bar + 8 * 32 + 32;

  const size_t dynBytes = 2 * HDIM * sizeof(float) + (8 * 32 + 64) * sizeof(unsigned);
  hipMemsetAsync(d_ws, 0, dynBytes, stream);  // zero h state + barrier generation state

  void* args[] = {&p};
  hipLaunchCooperativeKernel(reinterpret_cast<void*>(&rnn_kernel),
                             dim3(BLOCKS), dim3(THREADS), args, 0, stream);
}

// Round 4
// 6288.589 us; speedup vs baseline: 1.0658x; 1.0658x over previous
//
#include <hip/hip_runtime.h>

#define STEPS 96
#define HDIM 4096
#define IDIM 1024
#define BLOCKS 256
#define THREADS 1024
#define WAVES 16
#define ROWS_PER_BLOCK 16  // 1 row per wave

// ---------- bf16 pack/unpack ----------
__device__ inline unsigned short f2bf(float f) {
  unsigned u = __float_as_uint(f);
  u += 0x7fffu + ((u >> 16) & 1u);
  return (unsigned short)(u >> 16);
}
__device__ inline unsigned pack2(float a, float b) {
  return (unsigned)f2bf(a) | ((unsigned)f2bf(b) << 16);
}
__device__ inline float blo(unsigned p) { return __uint_as_float(p << 16); }
__device__ inline float bhi(unsigned p) { return __uint_as_float(p & 0xffff0000u); }

__device__ inline float wave_reduce(float v) {
#pragma unroll
  for (int off = 32; off > 0; off >>= 1) v += __shfl_xor(v, off);
  return v;
}

struct Params {
  const float *x, *Wih0, *bih0, *Whh0, *bhh0, *Wih1, *bih1, *Whh1, *bhh1, *Wfc, *bfc;
  float *h0, *h1;  // [HDIM] each, single-buffered (phases barrier-separated)
  unsigned *leaf, *root, *flag;
  float *out;
};

// monotonic hierarchical grid barrier; gen = 1,2,3,...
__device__ inline void grid_barrier(const Params& p, unsigned gen) {
  __syncthreads();
  if (threadIdx.x == 0) {
    __threadfence();
    const int g = blockIdx.x & 7;
    unsigned prev = __hip_atomic_fetch_add(p.leaf + g * 32, 1u, __ATOMIC_RELAXED,
                                           __HIP_MEMORY_SCOPE_AGENT);
    if (prev == gen * (BLOCKS / 8) - 1) {
      unsigned r = __hip_atomic_fetch_add(p.root, 1u, __ATOMIC_RELAXED,
                                          __HIP_MEMORY_SCOPE_AGENT);
      if (r == gen * 8 - 1) {
        __hip_atomic_store(p.flag, gen, __ATOMIC_RELEASE, __HIP_MEMORY_SCOPE_AGENT);
      }
    }
    while (__hip_atomic_load(p.flag, __ATOMIC_RELAXED, __HIP_MEMORY_SCOPE_AGENT) < gen) {
      __builtin_amdgcn_s_sleep(1);
    }
    __threadfence();
  }
  __syncthreads();
}

__global__ void __launch_bounds__(THREADS, 4) rnn_kernel(Params p) {
  // W_hh1 rows of this block, packed bf16: [r][j*128 + lane*2 + s] <-> cols (2u, 2u+1)
  __shared__ unsigned whh1[ROWS_PER_BLOCK * (HDIM / 2)];  // 128 KB
  __shared__ float win[IDIM + STEPS];
  __shared__ float red[WAVES];

  const int tid = threadIdx.x, lane = tid & 63, wv = tid >> 6, blk = blockIdx.x;
  const int row = blk * ROWS_PER_BLOCK + wv;  // this wave's row in all matrices

  // ---- setup: stage W_hh1 into LDS ----
  for (int rr = 0; rr < ROWS_PER_BLOCK; ++rr) {
    const float* src = p.Whh1 + (size_t)(blk * ROWS_PER_BLOCK + rr) * HDIM;
    for (int u = tid; u < HDIM / 2; u += THREADS) {
      float2 f = *reinterpret_cast<const float2*>(src + 2 * u);
      whh1[rr * (HDIM / 2) + u] = pack2(f.x, f.y);
    }
  }
  for (int i = tid; i < IDIM; i += THREADS) win[i] = p.x[i];

  // ---- setup: register-resident packed weights (72 VGPRs + 2 fc) ----
  unsigned w_ih0[8];
#pragma unroll
  for (int j = 0; j < 8; ++j) {
    const float* s = p.Wih0 + (size_t)row * IDIM + j * 128 + lane;
    w_ih0[j] = pack2(s[0], s[64]);
  }
  unsigned w_hh0[32], w_ih1[32];
#pragma unroll
  for (int j = 0; j < 16; ++j) {
    float4 f;
    f = *reinterpret_cast<const float4*>(p.Whh0 + (size_t)row * HDIM + j * 256 + lane * 4);
    w_hh0[2 * j] = pack2(f.x, f.y); w_hh0[2 * j + 1] = pack2(f.z, f.w);
    f = *reinterpret_cast<const float4*>(p.Wih1 + (size_t)row * HDIM + j * 256 + lane * 4);
    w_ih1[2 * j] = pack2(f.x, f.y); w_ih1[2 * j + 1] = pack2(f.z, f.w);
  }
  unsigned wfcp[2];
  {
    float4 f = *reinterpret_cast<const float4*>(p.Wfc + tid * 4);
    wfcp[0] = pack2(f.x, f.y); wfcp[1] = pack2(f.z, f.w);
  }
  const float bias0 = p.bih0[row] + p.bhh0[row];
  const float bias1 = p.bih1[row] + p.bhh1[row];
  const float bfc = p.bfc[0];

  __syncthreads();

  float p1 = 0.f;  // carried per-lane partial of Whh0 . h0 (zero at t=0)
  unsigned gen = 0;

  for (int t = 0; t < STEPS; ++t) {
    // ---- phase 1: h0 = tanh(Wih0 @ win[t:] + carried Whh0-partial + bias) ----
    float a1 = p1;
#pragma unroll
    for (int j = 0; j < 8; ++j) {
      float v0 = win[t + j * 128 + lane];
      float v1 = win[t + j * 128 + 64 + lane];
      a1 += v0 * blo(w_ih0[j]) + v1 * bhi(w_ih0[j]);
    }
    a1 = wave_reduce(a1);
    if (lane == 0) p.h0[row] = tanhf(a1 + bias0);

    // ---- slot 2 (pre-barrier): Whh1 @ h1_old from LDS weights ----
    float a2 = 0.f;
    {
      const unsigned* wl = whh1 + wv * (HDIM / 2);
#pragma unroll
      for (int j = 0; j < 16; ++j) {
        float4 v = *reinterpret_cast<const float4*>(p.h1 + j * 256 + lane * 4);
        unsigned c0 = wl[j * 128 + lane * 2], c1 = wl[j * 128 + lane * 2 + 1];
        a2 += v.x * blo(c0) + v.y * bhi(c0) + v.z * blo(c1) + v.w * bhi(c1);
      }
    }

    grid_barrier(p, ++gen);

    // ---- phase 2: += Wih1 @ h0 ; also next step's Whh0 @ h0 partial ----
    float q1 = 0.f;
#pragma unroll
    for (int j = 0; j < 16; ++j) {
      float4 v = *reinterpret_cast<const float4*>(p.h0 + j * 256 + lane * 4);
      a2 += v.x * blo(w_ih1[2 * j]) + v.y * bhi(w_ih1[2 * j]) +
            v.z * blo(w_ih1[2 * j + 1]) + v.w * bhi(w_ih1[2 * j + 1]);
      q1 += v.x * blo(w_hh0[2 * j]) + v.y * bhi(w_hh0[2 * j]) +
            v.z * blo(w_hh0[2 * j + 1]) + v.w * bhi(w_hh0[2 * j + 1]);
    }
    a2 = wave_reduce(a2);
    if (lane == 0) p.h1[row] = tanhf(a2 + bias1);
    p1 = q1;

    grid_barrier(p, ++gen);

    // ---- phase 3: y = Wfc @ h1 + b_fc (redundant per block), append ----
    {
      float4 v = *reinterpret_cast<const float4*>(p.h1 + tid * 4);
      float part = v.x * blo(wfcp[0]) + v.y * bhi(wfcp[0]) +
                   v.z * blo(wfcp[1]) + v.w * bhi(wfcp[1]);
      part = wave_reduce(part);
      if (lane == 0) red[wv] = part;
    }
    __syncthreads();
    if (tid == 0) {
      float y = bfc;
#pragma unroll
      for (int i = 0; i < WAVES; ++i) y += red[i];
      win[IDIM + t] = y;
      if (blk == 0) p.out[t] = y;
    }
    __syncthreads();
  }
}

extern "C" void kernel_launch(void* const* d_in, const int* in_sizes, int n_in,
                              void* d_out, int out_size, void* d_ws, size_t ws_size,
                              hipStream_t stream) {
  Params p;
  p.x = (const float*)d_in[0];
  p.Wih0 = (const float*)d_in[1];
  p.bih0 = (const float*)d_in[2];
  p.Whh0 = (const float*)d_in[3];
  p.bhh0 = (const float*)d_in[4];
  p.Wih1 = (const float*)d_in[5];
  p.bih1 = (const float*)d_in[6];
  p.Whh1 = (const float*)d_in[7];
  p.bhh1 = (const float*)d_in[8];
  p.Wfc = (const float*)d_in[9];
  p.bfc = (const float*)d_in[10];
  p.out = (float*)d_out;

  float* hbuf = (float*)d_ws;
  p.h0 = hbuf;
  p.h1 = hbuf + HDIM;
  unsigned* bar = (unsigned*)(hbuf + 2 * HDIM);
  p.leaf = bar;
  p.root = bar + 8 * 32;
  p.flag = bar + 8 * 32 + 32;

  const size_t dynBytes = 2 * HDIM * sizeof(float) + (8 * 32 + 64) * sizeof(unsigned);
  hipMemsetAsync(d_ws, 0, dynBytes, stream);  // zero h state + barrier state

  void* args[] = {&p};
  hipLaunchCooperativeKernel(reinterpret_cast<void*>(&rnn_kernel),
                             dim3(BLOCKS), dim3(THREADS), args, 0, stream);
}

// Round 5
// 5298.845 us; speedup vs baseline: 1.2649x; 1.1868x over previous
//
#include <hip/hip_runtime.h>

#define STEPS 96
#define HDIM 4096
#define IDIM 1024
#define BLOCKS 256
#define THREADS 1024
#define WAVES 16
#define ROWS_PER_BLOCK 16  // 1 row per wave

#define PIN(x) asm volatile("" : "+v"(x))

// ---------- bf16 pack/unpack ----------
__device__ inline unsigned short f2bf(float f) {
  unsigned u = __float_as_uint(f);
  u += 0x7fffu + ((u >> 16) & 1u);
  return (unsigned short)(u >> 16);
}
__device__ inline unsigned pack2(float a, float b) {
  return (unsigned)f2bf(a) | ((unsigned)f2bf(b) << 16);
}
__device__ inline float blo(unsigned p) { return __uint_as_float(p << 16); }
__device__ inline float bhi(unsigned p) { return __uint_as_float(p & 0xffff0000u); }

__device__ inline float wave_reduce(float v) {
#pragma unroll
  for (int off = 32; off > 0; off >>= 1) v += __shfl_xor(v, off);
  return v;
}

struct Params {
  const float *x, *Wih0, *bih0, *Whh0, *bhh0, *Wih1, *bih1, *Whh1, *bhh1, *Wfc, *bfc;
  float *h0, *h1;  // [HDIM] each in global ws
  unsigned *leaf, *root, *flag;
  float *out;
};

// monotonic hierarchical grid barrier; gen = 1,2,3,...
__device__ inline void grid_barrier(const Params& p, unsigned gen) {
  __syncthreads();
  if (threadIdx.x == 0) {
    __threadfence();
    const int g = blockIdx.x & 7;
    unsigned prev = __hip_atomic_fetch_add(p.leaf + g * 32, 1u, __ATOMIC_RELAXED,
                                           __HIP_MEMORY_SCOPE_AGENT);
    if (prev == gen * (BLOCKS / 8) - 1) {
      unsigned r = __hip_atomic_fetch_add(p.root, 1u, __ATOMIC_RELAXED,
                                          __HIP_MEMORY_SCOPE_AGENT);
      if (r == gen * 8 - 1) {
        __hip_atomic_store(p.flag, gen, __ATOMIC_RELEASE, __HIP_MEMORY_SCOPE_AGENT);
      }
    }
    while (__hip_atomic_load(p.flag, __ATOMIC_RELAXED, __HIP_MEMORY_SCOPE_AGENT) < gen) {
      __builtin_amdgcn_s_sleep(1);
    }
    __threadfence();
  }
  __syncthreads();
}

__global__ void __launch_bounds__(THREADS, 4) rnn_kernel(Params p) {
  // W_hh1 rows of this block, packed bf16: [r][j*128 + lane*2 + s] <-> cols (2u,2u+1)
  __shared__ unsigned whh1[ROWS_PER_BLOCK * (HDIM / 2)];  // 128 KB
  __shared__ float win[IDIM + STEPS];                     // 4.4 KB
  __shared__ float hstage[HDIM];                          // 16 KB, reused 3x per step
  __shared__ float red[WAVES];

  const int tid = threadIdx.x, lane = tid & 63, wv = tid >> 6, blk = blockIdx.x;
  const int row = blk * ROWS_PER_BLOCK + wv;

  // ---- setup: stage W_hh1 into LDS; zero hstage (h1_old at t=0); window ----
  for (int rr = 0; rr < ROWS_PER_BLOCK; ++rr) {
    const float* src = p.Whh1 + (size_t)(blk * ROWS_PER_BLOCK + rr) * HDIM;
    for (int u = tid; u < HDIM / 2; u += THREADS) {
      float2 f = *reinterpret_cast<const float2*>(src + 2 * u);
      whh1[rr * (HDIM / 2) + u] = pack2(f.x, f.y);
    }
  }
  for (int i = tid; i < HDIM; i += THREADS) hstage[i] = 0.f;
  for (int i = tid; i < IDIM; i += THREADS) win[i] = p.x[i];

  // ---- setup: register-resident packed weights, PINNED against remat ----
  unsigned w_ih0[8];
#pragma unroll
  for (int j = 0; j < 8; ++j) {
    const float* s = p.Wih0 + (size_t)row * IDIM + j * 128 + lane;
    w_ih0[j] = pack2(s[0], s[64]);
    PIN(w_ih0[j]);
  }
  unsigned w_hh0[32], w_ih1[32];
#pragma unroll
  for (int j = 0; j < 16; ++j) {
    float4 f;
    f = *reinterpret_cast<const float4*>(p.Whh0 + (size_t)row * HDIM + j * 256 + lane * 4);
    w_hh0[2 * j] = pack2(f.x, f.y); w_hh0[2 * j + 1] = pack2(f.z, f.w);
    PIN(w_hh0[2 * j]); PIN(w_hh0[2 * j + 1]);
    f = *reinterpret_cast<const float4*>(p.Wih1 + (size_t)row * HDIM + j * 256 + lane * 4);
    w_ih1[2 * j] = pack2(f.x, f.y); w_ih1[2 * j + 1] = pack2(f.z, f.w);
    PIN(w_ih1[2 * j]); PIN(w_ih1[2 * j + 1]);
  }
  unsigned wfcp[2];
  {
    float4 f = *reinterpret_cast<const float4*>(p.Wfc + tid * 4);
    wfcp[0] = pack2(f.x, f.y); wfcp[1] = pack2(f.z, f.w);
    PIN(wfcp[0]); PIN(wfcp[1]);
  }
  float bias0 = p.bih0[row] + p.bhh0[row];
  float bias1 = p.bih1[row] + p.bhh1[row];
  float bfc = p.bfc[0];
  PIN(bias0); PIN(bias1); PIN(bfc);

  __syncthreads();

  float p1 = 0.f;  // carried per-lane partial of Whh0 . h0 (zero at t=0)
  unsigned gen = 0;

  for (int t = 0; t < STEPS; ++t) {
    // ---- phase 1: h0 = tanh(Wih0 @ win[t:] + carried Whh0-partial + bias) ----
    float a1 = p1;
#pragma unroll
    for (int j = 0; j < 8; ++j) {
      float v0 = win[t + j * 128 + lane];
      float v1 = win[t + j * 128 + 64 + lane];
      a1 += v0 * blo(w_ih0[j]) + v1 * bhi(w_ih0[j]);
    }
    a1 = wave_reduce(a1);
    if (lane == 0) p.h0[row] = tanhf(a1 + bias0);

    // ---- slot 2 (pre-barrier): Whh1 @ h1_old, weights LDS, h1_old in hstage ----
    float a2 = 0.f;
    {
      const unsigned* wl = whh1 + wv * (HDIM / 2);
#pragma unroll
      for (int j = 0; j < 16; ++j) {
        float4 v = *reinterpret_cast<const float4*>(hstage + j * 256 + lane * 4);
        unsigned c0 = wl[j * 128 + lane * 2], c1 = wl[j * 128 + lane * 2 + 1];
        a2 += v.x * blo(c0) + v.y * bhi(c0) + v.z * blo(c1) + v.w * bhi(c1);
      }
    }

    grid_barrier(p, ++gen);  // h0 now globally complete; also hstage free

    // ---- phase 2: stage h0 -> LDS once per block; += Wih1 @ h0 ; next Whh0 partial ----
    {
      float4 v = *reinterpret_cast<const float4*>(p.h0 + tid * 4);
      *reinterpret_cast<float4*>(hstage + tid * 4) = v;
    }
    __syncthreads();
    float q1 = 0.f;
#pragma unroll
    for (int j = 0; j < 16; ++j) {
      float4 v = *reinterpret_cast<const float4*>(hstage + j * 256 + lane * 4);
      a2 += v.x * blo(w_ih1[2 * j]) + v.y * bhi(w_ih1[2 * j]) +
            v.z * blo(w_ih1[2 * j + 1]) + v.w * bhi(w_ih1[2 * j + 1]);
      q1 += v.x * blo(w_hh0[2 * j]) + v.y * bhi(w_hh0[2 * j]) +
            v.z * blo(w_hh0[2 * j + 1]) + v.w * bhi(w_hh0[2 * j + 1]);
    }
    a2 = wave_reduce(a2);
    if (lane == 0) p.h1[row] = tanhf(a2 + bias1);
    p1 = q1;

    grid_barrier(p, ++gen);  // h1 globally complete; hstage(h0) free

    // ---- phase 3: y = Wfc @ h1 + b_fc (redundant per block); restage h1 ----
    {
      float4 v = *reinterpret_cast<const float4*>(p.h1 + tid * 4);
      *reinterpret_cast<float4*>(hstage + tid * 4) = v;  // h1_old for next step
      float part = v.x * blo(wfcp[0]) + v.y * bhi(wfcp[0]) +
                   v.z * blo(wfcp[1]) + v.w * bhi(wfcp[1]);
      part = wave_reduce(part);
      if (lane == 0) red[wv] = part;
    }
    __syncthreads();
    if (tid == 0) {
      float y = bfc;
#pragma unroll
      for (int i = 0; i < WAVES; ++i) y += red[i];
      win[IDIM + t] = y;
      if (blk == 0) p.out[t] = y;
    }
    __syncthreads();
  }
}

extern "C" void kernel_launch(void* const* d_in, const int* in_sizes, int n_in,
                              void* d_out, int out_size, void* d_ws, size_t ws_size,
                              hipStream_t stream) {
  Params p;
  p.x = (const float*)d_in[0];
  p.Wih0 = (const float*)d_in[1];
  p.bih0 = (const float*)d_in[2];
  p.Whh0 = (const float*)d_in[3];
  p.bhh0 = (const float*)d_in[4];
  p.Wih1 = (const float*)d_in[5];
  p.bih1 = (const float*)d_in[6];
  p.Whh1 = (const float*)d_in[7];
  p.bhh1 = (const float*)d_in[8];
  p.Wfc = (const float*)d_in[9];
  p.bfc = (const float*)d_in[10];
  p.out = (float*)d_out;

  float* hbuf = (float*)d_ws;
  p.h0 = hbuf;
  p.h1 = hbuf + HDIM;
  unsigned* bar = (unsigned*)(hbuf + 2 * HDIM);
  p.leaf = bar;
  p.root = bar + 8 * 32;
  p.flag = bar + 8 * 32 + 32;

  // only the barrier state must be zeroed (h bufs are written before read)
  hipMemsetAsync(bar, 0, (8 * 32 + 64) * sizeof(unsigned), stream);

  void* args[] = {&p};
  hipLaunchCooperativeKernel(reinterpret_cast<void*>(&rnn_kernel),
                             dim3(BLOCKS), dim3(THREADS), args, 0, stream);
}

// Round 6
// 5290.870 us; speedup vs baseline: 1.2668x; 1.0015x over previous
//
#include <hip/hip_runtime.h>

#define STEPS 96
#define HDIM 4096
#define IDIM 1024
#define BLOCKS 256
#define THREADS 1024
#define WAVES 16
#define ROWS_PER_BLOCK 16  // 1 row per wave

#define PIN(x) asm volatile("" : "+v"(x))

// ---------- bf16 pack/unpack ----------
__device__ inline unsigned short f2bf(float f) {
  unsigned u = __float_as_uint(f);
  u += 0x7fffu + ((u >> 16) & 1u);
  return (unsigned short)(u >> 16);
}
__device__ inline unsigned pack2(float a, float b) {
  return (unsigned)f2bf(a) | ((unsigned)f2bf(b) << 16);
}
__device__ inline float blo(unsigned p) { return __uint_as_float(p << 16); }
__device__ inline float bhi(unsigned p) { return __uint_as_float(p & 0xffff0000u); }

__device__ inline float wave_reduce(float v) {
#pragma unroll
  for (int off = 32; off > 0; off >>= 1) v += __shfl_xor(v, off);
  return v;
}

struct Params {
  const float *x, *Wih0, *bih0, *Whh0, *bhh0, *Wih1, *bih1, *Whh1, *bhh1, *Wfc, *bfc;
  float *h0, *h1;  // [HDIM] each in global ws
  unsigned *leaf, *root, *flag;
  float *out;
};

// monotonic hierarchical grid barrier; gen = 1,2,3,...
__device__ inline void grid_barrier(const Params& p, unsigned gen) {
  __syncthreads();
  if (threadIdx.x == 0) {
    __threadfence();
    const int g = blockIdx.x & 7;
    unsigned prev = __hip_atomic_fetch_add(p.leaf + g * 32, 1u, __ATOMIC_RELAXED,
                                           __HIP_MEMORY_SCOPE_AGENT);
    if (prev == gen * (BLOCKS / 8) - 1) {
      unsigned r = __hip_atomic_fetch_add(p.root, 1u, __ATOMIC_RELAXED,
                                          __HIP_MEMORY_SCOPE_AGENT);
      if (r == gen * 8 - 1) {
        __hip_atomic_store(p.flag, gen, __ATOMIC_RELEASE, __HIP_MEMORY_SCOPE_AGENT);
      }
    }
    while (__hip_atomic_load(p.flag, __ATOMIC_RELAXED, __HIP_MEMORY_SCOPE_AGENT) < gen) {
      __builtin_amdgcn_s_sleep(1);
    }
    __threadfence();
  }
  __syncthreads();
}

__attribute__((amdgpu_waves_per_eu(4, 4)))
__global__ void __launch_bounds__(THREADS) rnn_kernel(Params p) {
  // W_hh1 rows of this block, packed bf16: [r][j*128 + lane*2 + s] <-> cols (2u,2u+1)
  __shared__ unsigned whh1[ROWS_PER_BLOCK * (HDIM / 2)];  // 128 KB
  __shared__ float win[IDIM + STEPS];                     // 4.4 KB
  __shared__ float hstage[HDIM];                          // 16 KB, reused 3x per step
  __shared__ float red[WAVES];

  const int tid = threadIdx.x, lane = tid & 63, wv = tid >> 6, blk = blockIdx.x;
  const int row = blk * ROWS_PER_BLOCK + wv;

  // ---- setup: stage W_hh1 into LDS; zero hstage (h1_old at t=0); window ----
  for (int rr = 0; rr < ROWS_PER_BLOCK; ++rr) {
    const float* src = p.Whh1 + (size_t)(blk * ROWS_PER_BLOCK + rr) * HDIM;
    for (int u = tid; u < HDIM / 2; u += THREADS) {
      float2 f = *reinterpret_cast<const float2*>(src + 2 * u);
      whh1[rr * (HDIM / 2) + u] = pack2(f.x, f.y);
    }
  }
  for (int i = tid; i < HDIM; i += THREADS) hstage[i] = 0.f;
  for (int i = tid; i < IDIM; i += THREADS) win[i] = p.x[i];

  // ---- setup: register-resident packed weights, PINNED against remat ----
  unsigned w_ih0[8];
#pragma unroll
  for (int j = 0; j < 8; ++j) {
    const float* s = p.Wih0 + (size_t)row * IDIM + j * 128 + lane;
    w_ih0[j] = pack2(s[0], s[64]);
    PIN(w_ih0[j]);
  }
  unsigned w_hh0[32], w_ih1[32];
#pragma unroll
  for (int j = 0; j < 16; ++j) {
    float4 f;
    f = *reinterpret_cast<const float4*>(p.Whh0 + (size_t)row * HDIM + j * 256 + lane * 4);
    w_hh0[2 * j] = pack2(f.x, f.y); w_hh0[2 * j + 1] = pack2(f.z, f.w);
    PIN(w_hh0[2 * j]); PIN(w_hh0[2 * j + 1]);
    f = *reinterpret_cast<const float4*>(p.Wih1 + (size_t)row * HDIM + j * 256 + lane * 4);
    w_ih1[2 * j] = pack2(f.x, f.y); w_ih1[2 * j + 1] = pack2(f.z, f.w);
    PIN(w_ih1[2 * j]); PIN(w_ih1[2 * j + 1]);
  }
  unsigned wfcp[2];
  {
    float4 f = *reinterpret_cast<const float4*>(p.Wfc + tid * 4);
    wfcp[0] = pack2(f.x, f.y); wfcp[1] = pack2(f.z, f.w);
    PIN(wfcp[0]); PIN(wfcp[1]);
  }
  float bias0 = p.bih0[row] + p.bhh0[row];
  float bias1 = p.bih1[row] + p.bhh1[row];
  float bfc = p.bfc[0];
  PIN(bias0); PIN(bias1); PIN(bfc);

  __syncthreads();

  float p1 = 0.f;  // carried per-lane partial of Whh0 . h0 (zero at t=0)
  unsigned gen = 0;

  for (int t = 0; t < STEPS; ++t) {
    // ---- phase 1: h0 = tanh(Wih0 @ win[t:] + carried Whh0-partial + bias) ----
    float a1 = p1;
#pragma unroll
    for (int j = 0; j < 8; ++j) {
      float v0 = win[t + j * 128 + lane];
      float v1 = win[t + j * 128 + 64 + lane];
      a1 += v0 * blo(w_ih0[j]) + v1 * bhi(w_ih0[j]);
    }
    a1 = wave_reduce(a1);
    if (lane == 0) p.h0[row] = tanhf(a1 + bias0);

    // ---- slot 2 (pre-barrier): Whh1 @ h1_old, weights LDS, h1_old in hstage ----
    float a2 = 0.f;
    {
      const unsigned* wl = whh1 + wv * (HDIM / 2);
#pragma unroll
      for (int j = 0; j < 16; ++j) {
        float4 v = *reinterpret_cast<const float4*>(hstage + j * 256 + lane * 4);
        unsigned c0 = wl[j * 128 + lane * 2], c1 = wl[j * 128 + lane * 2 + 1];
        a2 += v.x * blo(c0) + v.y * bhi(c0) + v.z * blo(c1) + v.w * bhi(c1);
      }
    }

    grid_barrier(p, ++gen);  // h0 now globally complete; also hstage free

    // ---- phase 2: stage h0 -> LDS once per block; += Wih1 @ h0 ; next Whh0 partial ----
    {
      float4 v = *reinterpret_cast<const float4*>(p.h0 + tid * 4);
      *reinterpret_cast<float4*>(hstage + tid * 4) = v;
    }
    __syncthreads();
    float q1 = 0.f;
#pragma unroll
    for (int j = 0; j < 16; ++j) {
      float4 v = *reinterpret_cast<const float4*>(hstage + j * 256 + lane * 4);
      a2 += v.x * blo(w_ih1[2 * j]) + v.y * bhi(w_ih1[2 * j]) +
            v.z * blo(w_ih1[2 * j + 1]) + v.w * bhi(w_ih1[2 * j + 1]);
      q1 += v.x * blo(w_hh0[2 * j]) + v.y * bhi(w_hh0[2 * j]) +
            v.z * blo(w_hh0[2 * j + 1]) + v.w * bhi(w_hh0[2 * j + 1]);
    }
    a2 = wave_reduce(a2);
    if (lane == 0) p.h1[row] = tanhf(a2 + bias1);
    p1 = q1;

    grid_barrier(p, ++gen);  // h1 globally complete; hstage(h0) free

    // ---- phase 3: y = Wfc @ h1 + b_fc (redundant per block); restage h1 ----
    {
      float4 v = *reinterpret_cast<const float4*>(p.h1 + tid * 4);
      *reinterpret_cast<float4*>(hstage + tid * 4) = v;  // h1_old for next step
      float part = v.x * blo(wfcp[0]) + v.y * bhi(wfcp[0]) +
                   v.z * blo(wfcp[1]) + v.w * bhi(wfcp[1]);
      part = wave_reduce(part);
      if (lane == 0) red[wv] = part;
    }
    __syncthreads();
    if (tid == 0) {
      float y = bfc;
#pragma unroll
      for (int i = 0; i < WAVES; ++i) y += red[i];
      win[IDIM + t] = y;
      if (blk == 0) p.out[t] = y;
    }
    __syncthreads();
  }
}

extern "C" void kernel_launch(void* const* d_in, const int* in_sizes, int n_in,
                              void* d_out, int out_size, void* d_ws, size_t ws_size,
                              hipStream_t stream) {
  Params p;
  p.x = (const float*)d_in[0];
  p.Wih0 = (const float*)d_in[1];
  p.bih0 = (const float*)d_in[2];
  p.Whh0 = (const float*)d_in[3];
  p.bhh0 = (const float*)d_in[4];
  p.Wih1 = (const float*)d_in[5];
  p.bih1 = (const float*)d_in[6];
  p.Whh1 = (const float*)d_in[7];
  p.bhh1 = (const float*)d_in[8];
  p.Wfc = (const float*)d_in[9];
  p.bfc = (const float*)d_in[10];
  p.out = (float*)d_out;

  float* hbuf = (float*)d_ws;
  p.h0 = hbuf;
  p.h1 = hbuf + HDIM;
  unsigned* bar = (unsigned*)(hbuf + 2 * HDIM);
  p.leaf = bar;
  p.root = bar + 8 * 32;
  p.flag = bar + 8 * 32 + 32;

  // only the barrier state must be zeroed (h bufs are written before read)
  hipMemsetAsync(bar, 0, (8 * 32 + 64) * sizeof(unsigned), stream);

  void* args[] = {&p};
  hipLaunchCooperativeKernel(reinterpret_cast<void*>(&rnn_kernel),
                             dim3(BLOCKS), dim3(THREADS), args, 0, stream);
}